// Round 1
// baseline (2796.492 us; speedup 1.0000x reference)
//
#include <hip/hip_runtime.h>
#include <cstddef>
#include <cmath>

#define SEQ 2048
#define DMODEL 256
#define NHEAD 4
#define DK 64
#define VDIM 512
#define DV 128
#define NB 2
#define FDIM 1024
#define NROWS (NB*SEQ)   // 4096

// ---------------- sin/cos tables ----------------
__global__ void tables_kernel(float* __restrict__ sint, float* __restrict__ cost)
{
    int idx = blockIdx.x * 256 + threadIdx.x;      // SEQ*DK = 131072
    if (idx >= SEQ * DK) return;
    int s = idx >> 6, d = idx & 63;
    int j = d >> 1;
    float a = powf(10000.f, -(float)j / 31.f);
    float arg = (float)s * a;
    sint[idx] = sinf(arg);
    cost[idx] = cosf(arg);
}

// ---------------- layernorm (one row / block, D=256) ----------------
__global__ __launch_bounds__(256) void ln_kernel(const float* __restrict__ x,
                                                 const float* __restrict__ w,
                                                 const float* __restrict__ b,
                                                 float* __restrict__ o)
{
    int row = blockIdx.x;
    int t = threadIdx.x;
    float v = x[(size_t)row * DMODEL + t];
    __shared__ float red[256];
    red[t] = v; __syncthreads();
    for (int st = 128; st > 0; st >>= 1) { if (t < st) red[t] += red[t + st]; __syncthreads(); }
    float mu = red[0] * (1.f / DMODEL);
    __syncthreads();
    red[t] = v * v; __syncthreads();
    for (int st = 128; st > 0; st >>= 1) { if (t < st) red[t] += red[t + st]; __syncthreads(); }
    float var = red[0] * (1.f / DMODEL) - mu * mu;
    o[(size_t)row * DMODEL + t] = (v - mu) * rsqrtf(var + 1e-5f) * w[t] + b[t];
}

// ---------------- generic tiled fp32 GEMM: C = A(MxK) @ B(KxN) ----------------
// epilogue: optional bias (per col), exact gelu, add matrix
template<int BIAS, int GELU, int ADD>
__global__ __launch_bounds__(256) void gemm_k(const float* __restrict__ A,
                                              const float* __restrict__ Bm,
                                              float* __restrict__ C,
                                              const float* __restrict__ bias,
                                              const float* __restrict__ add,
                                              int M, int N, int K)
{
    __shared__ float As[64][17];
    __shared__ float Bs[16][64];
    int bx = blockIdx.x, by = blockIdx.y;
    int tid = threadIdx.x;
    int tx = tid & 15, ty = tid >> 4;
    float acc[4][4] = {};
    for (int k0 = 0; k0 < K; k0 += 16) {
        #pragma unroll
        for (int l = tid; l < 1024; l += 256) {
            int m = l >> 4, kk = l & 15;
            As[m][kk] = A[(size_t)(by * 64 + m) * K + k0 + kk];
            int kb = l >> 6, n = l & 63;
            Bs[kb][n] = Bm[(size_t)(k0 + kb) * N + bx * 64 + n];
        }
        __syncthreads();
        #pragma unroll
        for (int kk = 0; kk < 16; ++kk) {
            float a0 = As[ty * 4 + 0][kk], a1 = As[ty * 4 + 1][kk];
            float a2 = As[ty * 4 + 2][kk], a3 = As[ty * 4 + 3][kk];
            float b0 = Bs[kk][tx * 4 + 0], b1v = Bs[kk][tx * 4 + 1];
            float b2v = Bs[kk][tx * 4 + 2], b3v = Bs[kk][tx * 4 + 3];
            acc[0][0] += a0 * b0;  acc[0][1] += a0 * b1v; acc[0][2] += a0 * b2v; acc[0][3] += a0 * b3v;
            acc[1][0] += a1 * b0;  acc[1][1] += a1 * b1v; acc[1][2] += a1 * b2v; acc[1][3] += a1 * b3v;
            acc[2][0] += a2 * b0;  acc[2][1] += a2 * b1v; acc[2][2] += a2 * b2v; acc[2][3] += a2 * b3v;
            acc[3][0] += a3 * b0;  acc[3][1] += a3 * b1v; acc[3][2] += a3 * b2v; acc[3][3] += a3 * b3v;
        }
        __syncthreads();
    }
    #pragma unroll
    for (int i = 0; i < 4; ++i) {
        int row = by * 64 + ty * 4 + i;
        #pragma unroll
        for (int j = 0; j < 4; ++j) {
            int col = bx * 64 + tx * 4 + j;
            float v = acc[i][j];
            if (BIAS) v += bias[col];
            if (GELU) v = 0.5f * v * (1.f + erff(v * 0.70710678118654752f));
            if (ADD)  v += add[(size_t)row * N + col];
            C[(size_t)row * N + col] = v;
        }
    }
}

// ---------------- theta shift (rotary), optional input scale ----------------
__global__ void theta_kernel(float* __restrict__ q, const float* __restrict__ sint,
                             const float* __restrict__ cost, float scale)
{
    int p = blockIdx.x * 256 + threadIdx.x;       // NROWS * DMODEL/2 pairs
    if (p >= NROWS * (DMODEL / 2)) return;
    int f2 = p & 127;
    int row = p >> 7;
    int s = row & (SEQ - 1);
    int f = f2 * 2;
    int dk = f & 63;
    size_t base = (size_t)row * DMODEL + f;
    float x1 = q[base] * scale;
    float x2 = q[base + 1] * scale;
    float c = cost[s * 64 + dk], sn = sint[s * 64 + dk];
    q[base]     = x1 * c - x2 * sn;
    q[base + 1] = x2 * c + x1 * sn;
}

// ---------------- fused retention core ----------------
// grid: (S/32, H, B); block 256.  Per block: 32 q-rows of one (b,h).
// Computes o = (Q K^T * decay-mask) V with denom clip, per-row RMS norm,
// swish gating by g, writes gated output to og (b,s,h*DV+dv).
__global__ __launch_bounds__(256) void retention_kernel(
    const float* __restrict__ qr, const float* __restrict__ kr,
    const float* __restrict__ v,  const float* __restrict__ g,
    float* __restrict__ og)
{
    int qt = blockIdx.x, h = blockIdx.y, b = blockIdx.z;
    int tid = threadIdx.x;
    int q0 = qt * 32;
    __shared__ __align__(16) float Qs[32][68];
    __shared__ __align__(16) float Ks[32][68];
    __shared__ float Vs[32][128];
    __shared__ float Sc[32][33];
    __shared__ float Red[32][8];

    int r = tid >> 3, tc = tid & 7;
    int sg = q0 + r;
    float dec = logf(1.f - exp2f(-5.f - (float)h));

    for (int l = tid; l < 32 * 64; l += 256) {
        int rr = l >> 6, d = l & 63;
        Qs[rr][d] = qr[((size_t)(b * SEQ + q0 + rr)) * DMODEL + h * 64 + d];
    }
    float acc[16];
    #pragma unroll
    for (int j = 0; j < 16; ++j) acc[j] = 0.f;
    float denp = 0.f;

    for (int ti = 0; ti <= qt; ++ti) {
        int t0 = ti * 32;
        for (int l = tid; l < 32 * 64; l += 256) {
            int rr = l >> 6, d = l & 63;
            Ks[rr][d] = kr[((size_t)(b * SEQ + t0 + rr)) * DMODEL + h * 64 + d];
        }
        for (int l = tid; l < 32 * 128; l += 256) {
            int rr = l >> 7, d = l & 127;
            Vs[rr][d] = v[((size_t)(b * SEQ + t0 + rr)) * VDIM + h * 128 + d];
        }
        __syncthreads();
        // scores: each thread -> 4 scores of row r
        #pragma unroll
        for (int i = 0; i < 4; ++i) {
            int tt = tc * 4 + i;
            int tg = t0 + tt;
            const float4* qrow = (const float4*)(&Qs[r][0]);
            const float4* krow = (const float4*)(&Ks[tt][0]);
            float dotv = 0.f;
            #pragma unroll
            for (int d4 = 0; d4 < 16; ++d4) {
                float4 av = qrow[d4], bv = krow[d4];
                dotv += av.x * bv.x + av.y * bv.y + av.z * bv.z + av.w * bv.w;
            }
            float w = (tg <= sg) ? __expf((float)(sg - tg) * dec) : 0.f;
            float sc = dotv * w;
            Sc[r][tt] = sc;
            denp += fabsf(sc);
        }
        __syncthreads();
        // PV: thread owns (row r, dv = tc + 8*j)
        #pragma unroll
        for (int tt = 0; tt < 32; ++tt) {
            float scv = Sc[r][tt];
            #pragma unroll
            for (int j = 0; j < 16; ++j) acc[j] += scv * Vs[tt][tc + 8 * j];
        }
        __syncthreads();
    }

    // denom reduce across the 8 threads of each row
    Red[r][tc] = denp;
    __syncthreads();
    float den = 0.f;
    #pragma unroll
    for (int i = 0; i < 8; ++i) den += Red[r][i];
    float rgeo = 1.f - exp2f(-5.f - (float)h);
    float cs = (1.f - __expf(dec * (float)(sg + 1))) / (1.f - rgeo);
    float invs = rsqrtf(cs);          // 1/sqrt(row-sum of decay mask)
    den *= invs;
    den = fmaxf(den, 1.f);
    float scale = invs / den;
    float ss = 0.f;
    #pragma unroll
    for (int j = 0; j < 16; ++j) { acc[j] *= scale; ss += acc[j] * acc[j]; }
    __syncthreads();
    Red[r][tc] = ss;
    __syncthreads();
    float tot = 0.f;
    #pragma unroll
    for (int i = 0; i < 8; ++i) tot += Red[r][i];
    float rms = rsqrtf(tot * (1.f / DV) + 1e-6f);

    size_t base = ((size_t)(b * SEQ + sg)) * VDIM + h * DV;
    #pragma unroll
    for (int j = 0; j < 16; ++j) {
        int dv = tc + 8 * j;
        float gv = g[base + dv];
        float sig = 1.f / (1.f + __expf(-gv));
        og[base + dv] = gv * sig * acc[j] * rms;
    }
}

extern "C" void kernel_launch(void* const* d_in, const int* in_sizes, int n_in,
                              void* d_out, int out_size, void* d_ws, size_t ws_size,
                              hipStream_t stream)
{
    const float* x0    = (const float*)d_in[0];
    const float* Wq    = (const float*)d_in[1];
    const float* Wk    = (const float*)d_in[2];
    const float* Wv    = (const float*)d_in[3];
    const float* Wg    = (const float*)d_in[4];
    const float* Wo    = (const float*)d_in[5];
    const float* ln1w  = (const float*)d_in[6];
    const float* ln1b  = (const float*)d_in[7];
    const float* ln2w  = (const float*)d_in[8];
    const float* ln2b  = (const float*)d_in[9];
    const float* W1    = (const float*)d_in[10];
    const float* b1    = (const float*)d_in[11];
    const float* W2    = (const float*)d_in[12];
    const float* b2    = (const float*)d_in[13];

    float* wsf = (float*)d_ws;
    size_t o = 0;
    float* sin_t = wsf + o; o += SEQ * DK;
    float* cos_t = wsf + o; o += SEQ * DK;
    float* xln   = wsf + o; o += (size_t)NROWS * DMODEL;   // also reused as h2 (ln2 out)
    float* qb    = wsf + o; o += (size_t)NROWS * DMODEL;   // qb..vb region reused as ff1
    float* kb    = wsf + o; o += (size_t)NROWS * DMODEL;
    float* vb    = wsf + o; o += (size_t)NROWS * VDIM;
    float* gb    = wsf + o; o += (size_t)NROWS * VDIM;
    float* ogb   = wsf + o; o += (size_t)NROWS * VDIM;
    float* yb    = wsf + o; o += (size_t)NROWS * DMODEL;
    float* xbuf  = wsf + o; o += (size_t)NROWS * DMODEL;
    float* ff1   = qb;      // overlay: q/k/v dead after retention (4M floats = ff1 size)
    float* h2    = xln;     // overlay: xln dead after projections

    tables_kernel<<<(SEQ * DK + 255) / 256, 256, 0, stream>>>(sin_t, cos_t);

    const float* xcur = x0;
    for (int i = 0; i < 3; ++i) {
        const float* Wqi = Wq + (size_t)i * DMODEL * DMODEL;
        const float* Wki = Wk + (size_t)i * DMODEL * DMODEL;
        const float* Wvi = Wv + (size_t)i * DMODEL * VDIM;
        const float* Wgi = Wg + (size_t)i * DMODEL * VDIM;
        const float* Woi = Wo + (size_t)i * VDIM * DMODEL;
        const float* W1i = W1 + (size_t)i * DMODEL * FDIM;
        const float* W2i = W2 + (size_t)i * FDIM * DMODEL;

        ln_kernel<<<NROWS, 256, 0, stream>>>(xcur, ln1w + i * DMODEL, ln1b + i * DMODEL, xln);

        gemm_k<0,0,0><<<dim3(DMODEL/64, NROWS/64), 256, 0, stream>>>(xln, Wqi, qb, nullptr, nullptr, NROWS, DMODEL, DMODEL);
        gemm_k<0,0,0><<<dim3(DMODEL/64, NROWS/64), 256, 0, stream>>>(xln, Wki, kb, nullptr, nullptr, NROWS, DMODEL, DMODEL);
        gemm_k<0,0,0><<<dim3(VDIM/64,  NROWS/64), 256, 0, stream>>>(xln, Wvi, vb, nullptr, nullptr, NROWS, VDIM, DMODEL);
        gemm_k<0,0,0><<<dim3(VDIM/64,  NROWS/64), 256, 0, stream>>>(xln, Wgi, gb, nullptr, nullptr, NROWS, VDIM, DMODEL);

        theta_kernel<<<(NROWS * DMODEL / 2 + 255) / 256, 256, 0, stream>>>(qb, sin_t, cos_t, 1.0f);
        theta_kernel<<<(NROWS * DMODEL / 2 + 255) / 256, 256, 0, stream>>>(kb, sin_t, cos_t, 0.125f); // DK^-0.5

        retention_kernel<<<dim3(SEQ/32, NHEAD, NB), 256, 0, stream>>>(qb, kb, vb, gb, ogb);

        // y = og @ Wo + x
        gemm_k<0,0,1><<<dim3(DMODEL/64, NROWS/64), 256, 0, stream>>>(ogb, Woi, yb, nullptr, xcur, NROWS, DMODEL, VDIM);

        ln_kernel<<<NROWS, 256, 0, stream>>>(yb, ln2w + i * DMODEL, ln2b + i * DMODEL, h2);

        // ff1 = gelu(h2 @ W1 + b1)
        gemm_k<1,1,0><<<dim3(FDIM/64, NROWS/64), 256, 0, stream>>>(h2, W1i, ff1, b1 + (size_t)i * FDIM, nullptr, NROWS, FDIM, DMODEL);

        // x_next = ff1 @ W2 + b2 + y
        float* xout = (i == 2) ? (float*)d_out : xbuf;
        gemm_k<1,0,1><<<dim3(DMODEL/64, NROWS/64), 256, 0, stream>>>(ff1, W2i, xout, b2 + (size_t)i * DMODEL, yb, NROWS, DMODEL, FDIM);

        xcur = xout;
    }
}

// Round 2
// 506.235 us; speedup vs baseline: 5.5241x; 5.5241x over previous
//
#include <hip/hip_runtime.h>
#include <hip/hip_bf16.h>
#include <cstddef>
#include <cmath>

#define SEQ 2048
#define DMODEL 256
#define NHEAD 4
#define DK 64
#define VDIM 512
#define DV 128
#define NB 2
#define FDIM 1024
#define NROWS (NB*SEQ)   // 4096

typedef unsigned short u16;
typedef __attribute__((ext_vector_type(8))) short short8;
typedef __attribute__((ext_vector_type(4))) float f32x4;

static __device__ __forceinline__ u16 f2b(float f) {
    union { float f; unsigned u; } c; c.f = f;
    unsigned r = c.u + 0x7fffu + ((c.u >> 16) & 1u);
    return (u16)(r >> 16);
}
static __device__ __forceinline__ float b2f(u16 u) {
    union { unsigned u; float f; } c; c.u = ((unsigned)u) << 16; return c.f;
}

// ---------------- sin/cos tables ----------------
__global__ void tables_kernel(float* __restrict__ sint, float* __restrict__ cost)
{
    int idx = blockIdx.x * 256 + threadIdx.x;      // SEQ*DK = 131072
    if (idx >= SEQ * DK) return;
    int s = idx >> 6, d = idx & 63;
    int j = d >> 1;
    float a = powf(10000.f, -(float)j / 31.f);
    float arg = (float)s * a;
    sint[idx] = sinf(arg);
    cost[idx] = cosf(arg);
}

// ---------------- weight convert+transpose: fp32 [L][K][N] -> bf16 [L][N][K] ----
__global__ __launch_bounds__(256) void wconv_kernel(const float* __restrict__ in,
                                                    u16* __restrict__ out, int K, int N)
{
    __shared__ float tile[32][33];
    int n0 = blockIdx.x * 32, k0 = blockIdx.y * 32;
    size_t base = (size_t)blockIdx.z * K * N;
    int tx = threadIdx.x, ty = threadIdx.y;
    #pragma unroll
    for (int r = 0; r < 4; ++r) {
        int kr = ty + r * 8;
        tile[kr][tx] = in[base + (size_t)(k0 + kr) * N + n0 + tx];
    }
    __syncthreads();
    #pragma unroll
    for (int r = 0; r < 4; ++r) {
        int nr = ty + r * 8;
        out[base + (size_t)(n0 + nr) * K + k0 + tx] = f2b(tile[tx][nr]);
    }
}

// ---------------- layernorm fp32 -> bf16 ----------------
__global__ __launch_bounds__(256) void ln_kernel(const float* __restrict__ x,
                                                 const float* __restrict__ w,
                                                 const float* __restrict__ b,
                                                 u16* __restrict__ o)
{
    int row = blockIdx.x;
    int t = threadIdx.x;
    float v = x[(size_t)row * DMODEL + t];
    __shared__ float red[256];
    red[t] = v; __syncthreads();
    for (int st = 128; st > 0; st >>= 1) { if (t < st) red[t] += red[t + st]; __syncthreads(); }
    float mu = red[0] * (1.f / DMODEL);
    __syncthreads();
    red[t] = v * v; __syncthreads();
    for (int st = 128; st > 0; st >>= 1) { if (t < st) red[t] += red[t + st]; __syncthreads(); }
    float var = red[0] * (1.f / DMODEL) - mu * mu;
    o[(size_t)row * DMODEL + t] = f2b((v - mu) * rsqrtf(var + 1e-5f) * w[t] + b[t]);
}

// ---------------- theta shift on bf16 pairs ----------------
__global__ void theta_kernel(u16* __restrict__ q, const float* __restrict__ sint,
                             const float* __restrict__ cost, float scale)
{
    int p = blockIdx.x * 256 + threadIdx.x;       // NROWS * 128 pairs
    if (p >= NROWS * (DMODEL / 2)) return;
    int f2 = p & 127;
    int row = p >> 7;
    int s = row & (SEQ - 1);
    int dk = (f2 * 2) & 63;
    unsigned* qp = (unsigned*)q;
    unsigned u = qp[p];
    float x1 = b2f((u16)(u & 0xffff)) * scale;
    float x2 = b2f((u16)(u >> 16)) * scale;
    float c = cost[s * 64 + dk], sn = sint[s * 64 + dk];
    float y1 = x1 * c - x2 * sn;
    float y2 = x2 * c + x1 * sn;
    qp[p] = (unsigned)f2b(y1) | ((unsigned)f2b(y2) << 16);
}

// ---------------- V transpose per head: vb [4096][512] -> vt [8][128][2048] ----
__global__ __launch_bounds__(256) void vtrans_kernel(const u16* __restrict__ vb,
                                                     u16* __restrict__ vt)
{
    __shared__ u16 tile[32][33];
    int s0 = blockIdx.x * 32, dv0 = blockIdx.y * 32, z = blockIdx.z; // z = b*4+h
    int b = z >> 2, h = z & 3;
    int tx = threadIdx.x, ty = threadIdx.y;
    #pragma unroll
    for (int r = 0; r < 4; ++r) {
        int sr = ty + r * 8;
        tile[sr][tx] = vb[((size_t)(b * SEQ + s0 + sr)) * VDIM + h * DV + dv0 + tx];
    }
    __syncthreads();
    #pragma unroll
    for (int r = 0; r < 4; ++r) {
        int nr = ty + r * 8;
        vt[((size_t)(z * DV + dv0 + nr)) * SEQ + s0 + tx] = tile[tx][nr];
    }
}

// ---------------- bf16 MFMA GEMM: C = A(MxK) @ Bt(NxK)^T ----------------
// 64x64 tile, BK=32, 4 waves (each 32x32). Epilogue: bias / exact gelu / fp32 add.
template<int BIAS, int GELU, int ADD, int OUTBF>
__global__ __launch_bounds__(256) void gemm_bf16(const u16* __restrict__ A,
                                                 const u16* __restrict__ Bt,
                                                 void* __restrict__ Cout,
                                                 const float* __restrict__ bias,
                                                 const float* __restrict__ add,
                                                 int M, int N, int K)
{
    __shared__ u16 As[64][40];
    __shared__ u16 Bs[64][40];
    int bx = blockIdx.x, by = blockIdx.y;
    int tid = threadIdx.x;
    int wave = tid >> 6, lane = tid & 63;
    int wm = wave & 1, wn = wave >> 1;
    int l15 = lane & 15, lg = lane >> 4;
    int arow = tid >> 2, aseg = tid & 3;
    f32x4 acc[2][2] = {};
    const u16* Ag = A + (size_t)(by * 64 + arow) * K + aseg * 8;
    const u16* Bg = Bt + (size_t)(bx * 64 + arow) * K + aseg * 8;
    for (int k0 = 0; k0 < K; k0 += 32) {
        short8 av = *(const short8*)(Ag + k0);
        short8 bv = *(const short8*)(Bg + k0);
        *(short8*)&As[arow][aseg * 8] = av;
        *(short8*)&Bs[arow][aseg * 8] = bv;
        __syncthreads();
        short8 af[2], bf[2];
        af[0] = *(const short8*)&As[wm * 32 + l15][lg * 8];
        af[1] = *(const short8*)&As[wm * 32 + 16 + l15][lg * 8];
        bf[0] = *(const short8*)&Bs[wn * 32 + l15][lg * 8];
        bf[1] = *(const short8*)&Bs[wn * 32 + 16 + l15][lg * 8];
        #pragma unroll
        for (int mi = 0; mi < 2; ++mi)
            #pragma unroll
            for (int ni = 0; ni < 2; ++ni)
                acc[mi][ni] = __builtin_amdgcn_mfma_f32_16x16x32_bf16(af[mi], bf[ni], acc[mi][ni], 0, 0, 0);
        __syncthreads();
    }
    #pragma unroll
    for (int mi = 0; mi < 2; ++mi)
        #pragma unroll
        for (int ni = 0; ni < 2; ++ni)
            #pragma unroll
            for (int r = 0; r < 4; ++r) {
                int row = by * 64 + wm * 32 + mi * 16 + lg * 4 + r;
                int col = bx * 64 + wn * 32 + ni * 16 + l15;
                float v = acc[mi][ni][r];
                if (BIAS) v += bias[col];
                if (GELU) v = 0.5f * v * (1.f + erff(v * 0.70710678118654752f));
                if (ADD)  v += add[(size_t)row * N + col];
                if (OUTBF) ((u16*)Cout)[(size_t)row * N + col] = f2b(v);
                else       ((float*)Cout)[(size_t)row * N + col] = v;
            }
}

// ---------------- MFMA retention ----------------
// grid (32 pairs, H, B), 256 threads = 4 waves. Block handles q-tiles {p, 63-p}
// (32 rows each) -> 65 kv-tiles per block, perfectly balanced.
// wave (wq, wv): 16 q-rows, 64 dv columns.
__global__ __launch_bounds__(256) void retention_mfma(
    const u16* __restrict__ qb, const u16* __restrict__ kb,
    const u16* __restrict__ vt, const u16* __restrict__ gb,
    u16* __restrict__ og)
{
    int pair = blockIdx.x, h = blockIdx.y, b = blockIdx.z;
    int tid = threadIdx.x;
    int wave = tid >> 6, lane = tid & 63;
    int wq = wave >> 1, wv = wave & 1;
    int l15 = lane & 15, lg = lane >> 4;

    __shared__ float P_lds[4][16][36];
    __shared__ float ssred[2][2][16];

    float rgeo = 1.f - exp2f(-5.f - (float)h);
    float dec2 = log2f(rgeo);                 // log2(r), r = decay base

    const u16* qbase  = qb + ((size_t)b * SEQ) * DMODEL + h * DK;
    const u16* kbase  = kb + ((size_t)b * SEQ) * DMODEL + h * DK;
    const u16* vtbase = vt + ((size_t)(b * NHEAD + h)) * DV * SEQ;

    for (int side = 0; side < 2; ++side) {
        int qt = side ? (63 - pair) : pair;
        int q0 = qt * 32 + wq * 16;

        short8 qf[2];
        qf[0] = *(const short8*)(qbase + (size_t)(q0 + l15) * DMODEL + lg * 8);
        qf[1] = *(const short8*)(qbase + (size_t)(q0 + l15) * DMODEL + 32 + lg * 8);

        f32x4 oacc[4] = {};
        float den[4] = {0.f, 0.f, 0.f, 0.f};
        float eqr[4];
        int qrow[4];
        #pragma unroll
        for (int r = 0; r < 4; ++r) {
            qrow[r] = q0 + lg * 4 + r;
            eqr[r] = exp2f(dec2 * (float)qrow[r]);   // r^q (tiny)
        }

        int ntiles = qt + 1;
        for (int ti = 0; ti < ntiles; ++ti) {
            int t0 = ti * 32;
            f32x4 sacc[2] = {};
            #pragma unroll
            for (int tt = 0; tt < 2; ++tt) {
                const u16* kr = kbase + (size_t)(t0 + tt * 16 + l15) * DMODEL + lg * 8;
                short8 kf0 = *(const short8*)(kr);
                short8 kf1 = *(const short8*)(kr + 32);
                sacc[tt] = __builtin_amdgcn_mfma_f32_16x16x32_bf16(qf[0], kf0, sacc[tt], 0, 0, 0);
                sacc[tt] = __builtin_amdgcn_mfma_f32_16x16x32_bf16(qf[1], kf1, sacc[tt], 0, 0, 0);
            }
            // V B-frags (issue early; L1/L2-resident)
            short8 vf[4];
            #pragma unroll
            for (int nt = 0; nt < 4; ++nt) {
                int dv = wv * 64 + nt * 16 + l15;
                vf[nt] = *(const short8*)(vtbase + (size_t)dv * SEQ + t0 + lg * 8);
            }
            // decay weight + denom + stash P in per-wave LDS
            #pragma unroll
            for (int tt = 0; tt < 2; ++tt) {
                int tg = t0 + tt * 16 + l15;
                float et = exp2f(dec2 * -(float)tg);   // r^-t (large, bounded)
                #pragma unroll
                for (int r = 0; r < 4; ++r) {
                    float w = (tg <= qrow[r]) ? eqr[r] * et : 0.f;
                    float sv = sacc[tt][r] * w;
                    den[r] += fabsf(sv);
                    P_lds[wave][lg * 4 + r][tt * 16 + l15] = sv;
                }
            }
            // re-layout: A-frag for PV (per-wave private region, program-ordered)
            f32x4 p0 = *(const f32x4*)&P_lds[wave][l15][lg * 8];
            f32x4 p1 = *(const f32x4*)&P_lds[wave][l15][lg * 8 + 4];
            short8 pa;
            pa[0] = (short)f2b(p0[0]); pa[1] = (short)f2b(p0[1]);
            pa[2] = (short)f2b(p0[2]); pa[3] = (short)f2b(p0[3]);
            pa[4] = (short)f2b(p1[0]); pa[5] = (short)f2b(p1[1]);
            pa[6] = (short)f2b(p1[2]); pa[7] = (short)f2b(p1[3]);
            #pragma unroll
            for (int nt = 0; nt < 4; ++nt)
                oacc[nt] = __builtin_amdgcn_mfma_f32_16x16x32_bf16(pa, vf[nt], oacc[nt], 0, 0, 0);
        }

        // reduce denom across the 16 lanes sharing each row
        #pragma unroll
        for (int r = 0; r < 4; ++r) {
            float d = den[r];
            d += __shfl_xor(d, 1); d += __shfl_xor(d, 2);
            d += __shfl_xor(d, 4); d += __shfl_xor(d, 8);
            den[r] = d;
        }
        // normalization scales + partial sum of squares
        float scl[4], ss[4];
        #pragma unroll
        for (int r = 0; r < 4; ++r) {
            float rp1 = exp2f(dec2 * (float)(qrow[r] + 1));
            float cs = (1.f - rp1) / (1.f - rgeo);
            float invs = rsqrtf(cs);
            float d = fmaxf(den[r] * invs, 1.f);
            scl[r] = invs / d;
            ss[r] = 0.f;
        }
        #pragma unroll
        for (int nt = 0; nt < 4; ++nt)
            #pragma unroll
            for (int r = 0; r < 4; ++r) {
                float v = oacc[nt][r] * scl[r];
                oacc[nt][r] = v;
                ss[r] += v * v;
            }
        #pragma unroll
        for (int r = 0; r < 4; ++r) {
            float s = ss[r];
            s += __shfl_xor(s, 1); s += __shfl_xor(s, 2);
            s += __shfl_xor(s, 4); s += __shfl_xor(s, 8);
            ss[r] = s;
        }
        if (l15 == 0) {
            #pragma unroll
            for (int r = 0; r < 4; ++r) ssred[wq][wv][lg * 4 + r] = ss[r];
        }
        __syncthreads();
        float rmsr[4];
        #pragma unroll
        for (int r = 0; r < 4; ++r) {
            float tot = ssred[wq][0][lg * 4 + r] + ssred[wq][1][lg * 4 + r];
            rmsr[r] = rsqrtf(tot * (1.f / DV) + 1e-6f);
        }
        // gate + write
        #pragma unroll
        for (int nt = 0; nt < 4; ++nt) {
            int dv = wv * 64 + nt * 16 + l15;
            #pragma unroll
            for (int r = 0; r < 4; ++r) {
                size_t idx = ((size_t)(b * SEQ + qrow[r])) * VDIM + h * DV + dv;
                float gv = b2f(gb[idx]);
                float sig = 1.f / (1.f + __expf(-gv));
                og[idx] = f2b(gv * sig * oacc[nt][r] * rmsr[r]);
            }
        }
        __syncthreads();   // protect ssred before next side
    }
}

extern "C" void kernel_launch(void* const* d_in, const int* in_sizes, int n_in,
                              void* d_out, int out_size, void* d_ws, size_t ws_size,
                              hipStream_t stream)
{
    const float* x0    = (const float*)d_in[0];
    const float* Wq    = (const float*)d_in[1];
    const float* Wk    = (const float*)d_in[2];
    const float* Wv    = (const float*)d_in[3];
    const float* Wg    = (const float*)d_in[4];
    const float* Wo    = (const float*)d_in[5];
    const float* ln1w  = (const float*)d_in[6];
    const float* ln1b  = (const float*)d_in[7];
    const float* ln2w  = (const float*)d_in[8];
    const float* ln2b  = (const float*)d_in[9];
    const float* W1    = (const float*)d_in[10];
    const float* b1    = (const float*)d_in[11];
    const float* W2    = (const float*)d_in[12];
    const float* b2    = (const float*)d_in[13];

    char* ws = (char*)d_ws;
    size_t off = 0;
    auto alloc = [&](size_t bytes) { char* p = ws + off; off += (bytes + 255) & ~(size_t)255; return p; };

    float* sin_t = (float*)alloc(SEQ * DK * 4);
    float* cos_t = (float*)alloc(SEQ * DK * 4);
    u16* wq_t = (u16*)alloc((size_t)3 * DMODEL * DMODEL * 2);
    u16* wk_t = (u16*)alloc((size_t)3 * DMODEL * DMODEL * 2);
    u16* wv_t = (u16*)alloc((size_t)3 * DMODEL * VDIM * 2);
    u16* wg_t = (u16*)alloc((size_t)3 * DMODEL * VDIM * 2);
    u16* wo_t = (u16*)alloc((size_t)3 * VDIM * DMODEL * 2);
    u16* w1_t = (u16*)alloc((size_t)3 * DMODEL * FDIM * 2);
    u16* w2_t = (u16*)alloc((size_t)3 * FDIM * DMODEL * 2);
    u16* xln  = (u16*)alloc((size_t)NROWS * DMODEL * 2);   // reused as h2
    u16* qb   = (u16*)alloc((size_t)NROWS * DMODEL * 2);   // qb..vt reused as ff1 (8MB)
    u16* kb   = (u16*)alloc((size_t)NROWS * DMODEL * 2);
    u16* vt   = (u16*)alloc((size_t)NB * NHEAD * DV * SEQ * 2);
    u16* vb   = (u16*)alloc((size_t)NROWS * VDIM * 2);
    u16* gb   = (u16*)alloc((size_t)NROWS * VDIM * 2);
    u16* ogb  = (u16*)alloc((size_t)NROWS * VDIM * 2);
    float* yb   = (float*)alloc((size_t)NROWS * DMODEL * 4);
    float* xbuf = (float*)alloc((size_t)NROWS * DMODEL * 4);
    u16* ff1 = qb;
    u16* h2  = xln;

    tables_kernel<<<(SEQ * DK + 255) / 256, 256, 0, stream>>>(sin_t, cos_t);
    dim3 tb(32, 8);
    wconv_kernel<<<dim3(DMODEL/32, DMODEL/32, 3), tb, 0, stream>>>(Wq, wq_t, DMODEL, DMODEL);
    wconv_kernel<<<dim3(DMODEL/32, DMODEL/32, 3), tb, 0, stream>>>(Wk, wk_t, DMODEL, DMODEL);
    wconv_kernel<<<dim3(VDIM/32,  DMODEL/32, 3), tb, 0, stream>>>(Wv, wv_t, DMODEL, VDIM);
    wconv_kernel<<<dim3(VDIM/32,  DMODEL/32, 3), tb, 0, stream>>>(Wg, wg_t, DMODEL, VDIM);
    wconv_kernel<<<dim3(DMODEL/32, VDIM/32,  3), tb, 0, stream>>>(Wo, wo_t, VDIM, DMODEL);
    wconv_kernel<<<dim3(FDIM/32,  DMODEL/32, 3), tb, 0, stream>>>(W1, w1_t, DMODEL, FDIM);
    wconv_kernel<<<dim3(DMODEL/32, FDIM/32,  3), tb, 0, stream>>>(W2, w2_t, FDIM, DMODEL);

    const float* xcur = x0;
    for (int i = 0; i < 3; ++i) {
        const u16* wqi = wq_t + (size_t)i * DMODEL * DMODEL;
        const u16* wki = wk_t + (size_t)i * DMODEL * DMODEL;
        const u16* wvi = wv_t + (size_t)i * DMODEL * VDIM;
        const u16* wgi = wg_t + (size_t)i * DMODEL * VDIM;
        const u16* woi = wo_t + (size_t)i * VDIM * DMODEL;
        const u16* w1i = w1_t + (size_t)i * DMODEL * FDIM;
        const u16* w2i = w2_t + (size_t)i * FDIM * DMODEL;

        ln_kernel<<<NROWS, 256, 0, stream>>>(xcur, ln1w + i * DMODEL, ln1b + i * DMODEL, xln);

        gemm_bf16<0,0,0,1><<<dim3(DMODEL/64, NROWS/64), 256, 0, stream>>>(xln, wqi, qb, nullptr, nullptr, NROWS, DMODEL, DMODEL);
        gemm_bf16<0,0,0,1><<<dim3(DMODEL/64, NROWS/64), 256, 0, stream>>>(xln, wki, kb, nullptr, nullptr, NROWS, DMODEL, DMODEL);
        gemm_bf16<0,0,0,1><<<dim3(VDIM/64,  NROWS/64), 256, 0, stream>>>(xln, wvi, vb, nullptr, nullptr, NROWS, VDIM, DMODEL);
        gemm_bf16<0,0,0,1><<<dim3(VDIM/64,  NROWS/64), 256, 0, stream>>>(xln, wgi, gb, nullptr, nullptr, NROWS, VDIM, DMODEL);

        theta_kernel<<<(NROWS * 128 + 255) / 256, 256, 0, stream>>>(qb, sin_t, cos_t, 1.0f);
        theta_kernel<<<(NROWS * 128 + 255) / 256, 256, 0, stream>>>(kb, sin_t, cos_t, 0.125f);

        vtrans_kernel<<<dim3(SEQ/32, DV/32, NB*NHEAD), tb, 0, stream>>>(vb, vt);

        retention_mfma<<<dim3(32, NHEAD, NB), 256, 0, stream>>>(qb, kb, vt, gb, ogb);

        gemm_bf16<0,0,1,0><<<dim3(DMODEL/64, NROWS/64), 256, 0, stream>>>(ogb, woi, yb, nullptr, xcur, NROWS, DMODEL, VDIM);

        ln_kernel<<<NROWS, 256, 0, stream>>>(yb, ln2w + i * DMODEL, ln2b + i * DMODEL, h2);

        gemm_bf16<1,1,0,1><<<dim3(FDIM/64, NROWS/64), 256, 0, stream>>>(h2, w1i, ff1, b1 + (size_t)i * FDIM, nullptr, NROWS, FDIM, DMODEL);

        float* xout = (i == 2) ? (float*)d_out : xbuf;
        gemm_bf16<1,0,1,0><<<dim3(DMODEL/64, NROWS/64), 256, 0, stream>>>(ff1, w2i, xout, b2 + (size_t)i * DMODEL, yb, NROWS, DMODEL, FDIM);

        xcur = xout;
    }
}

// Round 3
// 488.760 us; speedup vs baseline: 5.7216x; 1.0358x over previous
//
#include <hip/hip_runtime.h>
#include <cstddef>
#include <cmath>
#include <algorithm>

#define SEQ 2048
#define DMODEL 256
#define NHEAD 4
#define DK 64
#define VDIM 512
#define DV 128
#define NB 2
#define FDIM 1024
#define NROWS (NB*SEQ)   // 4096
#define QKVGN 1536       // 256 q + 256 k + 512 v + 512 g
#define NSLOT 160        // sum over qt of (qt/16 + 1)

typedef unsigned short u16;
typedef __attribute__((ext_vector_type(8))) short short8;
typedef __attribute__((ext_vector_type(4))) float f32x4;

static __device__ __forceinline__ u16 f2b(float f) {
    union { float f; unsigned u; } c; c.f = f;
    unsigned r = c.u + 0x7fffu + ((c.u >> 16) & 1u);
    return (u16)(r >> 16);
}
static __device__ __forceinline__ float b2f(u16 u) {
    union { unsigned u; float f; } c; c.u = ((unsigned)u) << 16; return c.f;
}

// ---------------- sin/cos tables ----------------
__global__ void tables_kernel(float* __restrict__ sint, float* __restrict__ cost)
{
    int idx = blockIdx.x * 256 + threadIdx.x;      // SEQ*DK = 131072
    if (idx >= SEQ * DK) return;
    int s = idx >> 6, d = idx & 63;
    int j = d >> 1;
    float a = powf(10000.f, -(float)j / 31.f);
    float arg = (float)s * a;
    sint[idx] = sinf(arg);
    cost[idx] = cosf(arg);
}

// ------- weight convert+transpose: fp32 [K][N] -> bf16 [N][K], per-layer strides -------
__global__ __launch_bounds__(256) void wconv_kernel(const float* __restrict__ in,
                                                    u16* __restrict__ out, int K, int N,
                                                    size_t in_lstride, size_t out_lstride)
{
    __shared__ float tile[32][33];
    int n0 = blockIdx.x * 32, k0 = blockIdx.y * 32;
    const float* inz = in + (size_t)blockIdx.z * in_lstride;
    u16* outz = out + (size_t)blockIdx.z * out_lstride;
    int tx = threadIdx.x, ty = threadIdx.y;
    #pragma unroll
    for (int r = 0; r < 4; ++r) {
        int kr = ty + r * 8;
        tile[kr][tx] = inz[(size_t)(k0 + kr) * N + n0 + tx];
    }
    __syncthreads();
    #pragma unroll
    for (int r = 0; r < 4; ++r) {
        int nr = ty + r * 8;
        outz[(size_t)(n0 + nr) * K + k0 + tx] = f2b(tile[tx][nr]);
    }
}

// ---------------- plain layernorm fp32 -> bf16 ----------------
__global__ __launch_bounds__(256) void ln_kernel(const float* __restrict__ x,
                                                 const float* __restrict__ w,
                                                 const float* __restrict__ b,
                                                 u16* __restrict__ o)
{
    int row = blockIdx.x;
    int t = threadIdx.x;
    float v = x[(size_t)row * DMODEL + t];
    __shared__ float red[256];
    red[t] = v; __syncthreads();
    for (int st = 128; st > 0; st >>= 1) { if (t < st) red[t] += red[t + st]; __syncthreads(); }
    float mu = red[0] * (1.f / DMODEL);
    __syncthreads();
    red[t] = v * v; __syncthreads();
    for (int st = 128; st > 0; st >>= 1) { if (t < st) red[t] += red[t + st]; __syncthreads(); }
    float var = red[0] * (1.f / DMODEL) - mu * mu;
    o[(size_t)row * DMODEL + t] = f2b((v - mu) * rsqrtf(var + 1e-5f) * w[t] + b[t]);
}

// -------- combine 2 Wo split-K partials + residual -> yb, then LN2 -> bf16 --------
__global__ __launch_bounds__(256) void lncomb2_kernel(const float* __restrict__ pW,
                                                      const float* __restrict__ res,
                                                      const float* __restrict__ w,
                                                      const float* __restrict__ b,
                                                      float* __restrict__ yout,
                                                      u16* __restrict__ o)
{
    int row = blockIdx.x;
    int t = threadIdx.x;
    size_t i = (size_t)row * DMODEL + t;
    float v = pW[i] + pW[i + (size_t)NROWS * DMODEL] + res[i];
    yout[i] = v;
    __shared__ float red[256];
    red[t] = v; __syncthreads();
    for (int st = 128; st > 0; st >>= 1) { if (t < st) red[t] += red[t + st]; __syncthreads(); }
    float mu = red[0] * (1.f / DMODEL);
    __syncthreads();
    red[t] = v * v; __syncthreads();
    for (int st = 128; st > 0; st >>= 1) { if (t < st) red[t] += red[t + st]; __syncthreads(); }
    float var = red[0] * (1.f / DMODEL) - mu * mu;
    o[i] = f2b((v - mu) * rsqrtf(var + 1e-5f) * w[t] + b[t]);
}

// ---- combine 4 W2 split-K partials + bias + residual -> xbuf, then LN1(next) -> bf16 ----
__global__ __launch_bounds__(256) void lncomb4_kernel(const float* __restrict__ pW,
                                                      const float* __restrict__ bias,
                                                      const float* __restrict__ yb,
                                                      const float* __restrict__ w,
                                                      const float* __restrict__ b,
                                                      float* __restrict__ xout,
                                                      u16* __restrict__ o)
{
    int row = blockIdx.x;
    int t = threadIdx.x;
    size_t i = (size_t)row * DMODEL + t;
    const size_t PS = (size_t)NROWS * DMODEL;
    float v = pW[i] + pW[i + PS] + pW[i + 2 * PS] + pW[i + 3 * PS] + bias[t] + yb[i];
    xout[i] = v;
    __shared__ float red[256];
    red[t] = v; __syncthreads();
    for (int st = 128; st > 0; st >>= 1) { if (t < st) red[t] += red[t + st]; __syncthreads(); }
    float mu = red[0] * (1.f / DMODEL);
    __syncthreads();
    red[t] = v * v; __syncthreads();
    for (int st = 128; st > 0; st >>= 1) { if (t < st) red[t] += red[t + st]; __syncthreads(); }
    float var = red[0] * (1.f / DMODEL) - mu * mu;
    o[i] = f2b((v - mu) * rsqrtf(var + 1e-5f) * w[t] + b[t]);
}

// ---- final: combine 4 W2 partials + bias + residual -> d_out (fp32) ----
__global__ __launch_bounds__(256) void comb4_kernel(const float* __restrict__ pW,
                                                    const float* __restrict__ bias,
                                                    const float* __restrict__ yb,
                                                    float* __restrict__ out)
{
    int row = blockIdx.x;
    int t = threadIdx.x;
    size_t i = (size_t)row * DMODEL + t;
    const size_t PS = (size_t)NROWS * DMODEL;
    out[i] = pW[i] + pW[i + PS] + pW[i + 2 * PS] + pW[i + 3 * PS] + bias[t] + yb[i];
}

// ---- V transpose per head: qkvg v-cols -> vt [8][128][2048] bf16 ----
__global__ __launch_bounds__(256) void vtrans_kernel(const u16* __restrict__ qkvg,
                                                     u16* __restrict__ vt)
{
    __shared__ u16 tile[32][33];
    int s0 = blockIdx.x * 32, dv0 = blockIdx.y * 32, z = blockIdx.z; // z = b*4+h
    int b = z >> 2, h = z & 3;
    int tx = threadIdx.x, ty = threadIdx.y;
    #pragma unroll
    for (int r = 0; r < 4; ++r) {
        int sr = ty + r * 8;
        tile[sr][tx] = qkvg[((size_t)(b * SEQ + s0 + sr)) * QKVGN + 512 + h * DV + dv0 + tx];
    }
    __syncthreads();
    #pragma unroll
    for (int r = 0; r < 4; ++r) {
        int nr = ty + r * 8;
        vt[((size_t)(z * DV + dv0 + nr)) * SEQ + s0 + tx] = tile[tx][nr];
    }
}

// ---------------- bf16 MFMA GEMM: C = A(MxK) @ Bt(NxK)^T ----------------
// 64x64 tile, BK=32, 4 waves. ROT: rotary epilogue for cols<512 (q scale 1, k scale .125).
// SPLIT: blockIdx.z k-slice of kslice, fp32 partial out at z*M*N, no epilogue.
template<int BIAS, int GELU, int ROT, int OUTBF, int SPLIT>
__global__ __launch_bounds__(256) void gemm_bf16(const u16* __restrict__ A,
                                                 const u16* __restrict__ Bt,
                                                 void* __restrict__ Cout,
                                                 const float* __restrict__ bias,
                                                 const float* __restrict__ sint,
                                                 const float* __restrict__ cost,
                                                 int M, int N, int K, int kslice)
{
    __shared__ u16 As[64][40];
    __shared__ u16 Bs[64][40];
    int bx = blockIdx.x, by = blockIdx.y;
    int tid = threadIdx.x;
    int wave = tid >> 6, lane = tid & 63;
    int wm = wave & 1, wn = wave >> 1;
    int l15 = lane & 15, lg = lane >> 4;
    int arow = tid >> 2, aseg = tid & 3;
    f32x4 acc[2][2] = {};
    int kb0 = SPLIT ? blockIdx.z * kslice : 0;
    int kcnt = SPLIT ? kslice : K;
    const u16* Ag = A + (size_t)(by * 64 + arow) * K + kb0 + aseg * 8;
    const u16* Bg = Bt + (size_t)(bx * 64 + arow) * K + kb0 + aseg * 8;
    for (int k0 = 0; k0 < kcnt; k0 += 32) {
        short8 av = *(const short8*)(Ag + k0);
        short8 bv = *(const short8*)(Bg + k0);
        *(short8*)&As[arow][aseg * 8] = av;
        *(short8*)&Bs[arow][aseg * 8] = bv;
        __syncthreads();
        short8 af[2], bf[2];
        af[0] = *(const short8*)&As[wm * 32 + l15][lg * 8];
        af[1] = *(const short8*)&As[wm * 32 + 16 + l15][lg * 8];
        bf[0] = *(const short8*)&Bs[wn * 32 + l15][lg * 8];
        bf[1] = *(const short8*)&Bs[wn * 32 + 16 + l15][lg * 8];
        #pragma unroll
        for (int mi = 0; mi < 2; ++mi)
            #pragma unroll
            for (int ni = 0; ni < 2; ++ni)
                acc[mi][ni] = __builtin_amdgcn_mfma_f32_16x16x32_bf16(af[mi], bf[ni], acc[mi][ni], 0, 0, 0);
        __syncthreads();
    }
    float* Cf = (float*)Cout;
    if (SPLIT) Cf += (size_t)blockIdx.z * M * N;
    #pragma unroll
    for (int mi = 0; mi < 2; ++mi)
        #pragma unroll
        for (int ni = 0; ni < 2; ++ni)
            #pragma unroll
            for (int r = 0; r < 4; ++r) {
                int row = by * 64 + wm * 32 + mi * 16 + lg * 4 + r;
                int col = bx * 64 + wn * 32 + ni * 16 + l15;
                float v = acc[mi][ni][r];
                if (ROT) {
                    float pv = __shfl_xor(v, 1);   // partner (col^1), all lanes participate
                    if (col < 512) {
                        int s = row & (SEQ - 1);
                        int dk = col & 63;
                        float c = cost[(s << 6) + dk], sn = sint[(s << 6) + dk];
                        float rv = (col & 1) ? (v * c + pv * sn) : (v * c - pv * sn);
                        v = (col < 256) ? rv : rv * 0.125f;   // k gets DK^-0.5
                    }
                }
                if (BIAS) v += bias[col];
                if (GELU) v = 0.5f * v * (1.f + erff(v * 0.70710678118654752f));
                if (OUTBF) ((u16*)Cout)[(size_t)row * N + col] = f2b(v);
                else       Cf[(size_t)row * N + col] = v;
            }
}

// ---------------- retention pass 1: partial O + partial denom per kv-chunk ----------------
// blockIdx.x = slot in [0,160): enumerates (qt, chunk) with chunk of 16 kv-tiles.
// blockIdx.y = b*4+h. 4 waves: wq (2) x wv (2); wave = 16 q-rows x 64 dv.
__global__ __launch_bounds__(256) void retention_p1(
    const u16* __restrict__ qkvg, const u16* __restrict__ vt,
    float* __restrict__ po, float* __restrict__ pden)
{
    int f = blockIdx.x;
    int a, segs;
    if (f < 16)      { a = 0; segs = f; }
    else if (f < 48) { a = 1; segs = f - 16; }
    else if (f < 96) { a = 2; segs = f - 48; }
    else             { a = 3; segs = f - 96; }
    int qt = 16 * a + segs / (a + 1);
    int ch = segs % (a + 1);
    int bh = blockIdx.y, b = bh >> 2, h = bh & 3;
    int slot = bh * NSLOT + f;

    int tid = threadIdx.x;
    int wave = tid >> 6, lane = tid & 63;
    int wq = wave >> 1, wv = wave & 1;
    int l15 = lane & 15, lg = lane >> 4;

    __shared__ float P_lds[4][16][36];

    float rgeo = 1.f - exp2f(-5.f - (float)h);
    float dec2 = log2f(rgeo);

    const u16* qbase  = qkvg + (size_t)b * SEQ * QKVGN + h * 64;
    const u16* kbase  = qbase + 256;
    const u16* vtbase = vt + (size_t)bh * DV * SEQ;

    int q0 = qt * 32 + wq * 16;
    short8 qf[2];
    qf[0] = *(const short8*)(qbase + (size_t)(q0 + l15) * QKVGN + lg * 8);
    qf[1] = *(const short8*)(qbase + (size_t)(q0 + l15) * QKVGN + 32 + lg * 8);

    f32x4 oacc[4] = {};
    float den[4] = {0.f, 0.f, 0.f, 0.f};
    float eqr[4];
    int qrow[4];
    #pragma unroll
    for (int r = 0; r < 4; ++r) {
        qrow[r] = q0 + lg * 4 + r;
        eqr[r] = exp2f(dec2 * (float)qrow[r]);
    }

    int t_begin = ch * 16;
    int t_last = min(qt, t_begin + 15);
    for (int ti = t_begin; ti <= t_last; ++ti) {
        int t0 = ti * 32;
        f32x4 sacc[2] = {};
        #pragma unroll
        for (int tt = 0; tt < 2; ++tt) {
            const u16* kr = kbase + (size_t)(t0 + tt * 16 + l15) * QKVGN + lg * 8;
            short8 kf0 = *(const short8*)(kr);
            short8 kf1 = *(const short8*)(kr + 32);
            sacc[tt] = __builtin_amdgcn_mfma_f32_16x16x32_bf16(qf[0], kf0, sacc[tt], 0, 0, 0);
            sacc[tt] = __builtin_amdgcn_mfma_f32_16x16x32_bf16(qf[1], kf1, sacc[tt], 0, 0, 0);
        }
        short8 vf[4];
        #pragma unroll
        for (int nt = 0; nt < 4; ++nt) {
            int dv = wv * 64 + nt * 16 + l15;
            vf[nt] = *(const short8*)(vtbase + (size_t)dv * SEQ + t0 + lg * 8);
        }
        #pragma unroll
        for (int tt = 0; tt < 2; ++tt) {
            int tg = t0 + tt * 16 + l15;
            float et = exp2f(dec2 * -(float)tg);
            #pragma unroll
            for (int r = 0; r < 4; ++r) {
                float w = (tg <= qrow[r]) ? eqr[r] * et : 0.f;
                float sv = sacc[tt][r] * w;
                den[r] += fabsf(sv);
                P_lds[wave][lg * 4 + r][tt * 16 + l15] = sv;
            }
        }
        f32x4 p0 = *(const f32x4*)&P_lds[wave][l15][lg * 8];
        f32x4 p1 = *(const f32x4*)&P_lds[wave][l15][lg * 8 + 4];
        short8 pa;
        pa[0] = (short)f2b(p0[0]); pa[1] = (short)f2b(p0[1]);
        pa[2] = (short)f2b(p0[2]); pa[3] = (short)f2b(p0[3]);
        pa[4] = (short)f2b(p1[0]); pa[5] = (short)f2b(p1[1]);
        pa[6] = (short)f2b(p1[2]); pa[7] = (short)f2b(p1[3]);
        #pragma unroll
        for (int nt = 0; nt < 4; ++nt)
            oacc[nt] = __builtin_amdgcn_mfma_f32_16x16x32_bf16(pa, vf[nt], oacc[nt], 0, 0, 0);
    }

    #pragma unroll
    for (int r = 0; r < 4; ++r) {
        float d = den[r];
        d += __shfl_xor(d, 1); d += __shfl_xor(d, 2);
        d += __shfl_xor(d, 4); d += __shfl_xor(d, 8);
        den[r] = d;
    }
    if (l15 == 0) {
        #pragma unroll
        for (int r = 0; r < 4; ++r)
            pden[(size_t)slot * 32 + wq * 16 + lg * 4 + r] = den[r];
    }
    float* pobase = po + (size_t)slot * (32 * 128);
    #pragma unroll
    for (int nt = 0; nt < 4; ++nt)
        #pragma unroll
        for (int r = 0; r < 4; ++r)
            pobase[(wq * 16 + lg * 4 + r) * 128 + wv * 64 + nt * 16 + l15] = oacc[nt][r];
}

// ---------------- retention pass 2: reduce chunks, denom clip, RMS, swish gate ----------------
__global__ __launch_bounds__(256) void retention_p2(
    const float* __restrict__ po, const float* __restrict__ pden,
    const u16* __restrict__ qkvg, u16* __restrict__ og)
{
    int qt = blockIdx.x, bh = blockIdx.y, b = bh >> 2, h = bh & 3;
    int aa = qt >> 4, rr = qt & 15;
    int sbase = bh * NSLOT + qt + 8 * aa * (aa - 1) + rr * aa;
    int nch = aa + 1;
    int t = threadIdx.x;
    int row = t >> 3, c0 = (t & 7) * 16;
    int q = qt * 32 + row;

    float den = 0.f;
    for (int k = 0; k < nch; ++k) den += pden[(size_t)(sbase + k) * 32 + row];
    float acc[16];
    #pragma unroll
    for (int j = 0; j < 16; ++j) acc[j] = 0.f;
    for (int k = 0; k < nch; ++k) {
        const float* p = po + (size_t)(sbase + k) * (32 * 128) + row * 128 + c0;
        #pragma unroll
        for (int j = 0; j < 16; ++j) acc[j] += p[j];
    }
    float rgeo = 1.f - exp2f(-5.f - (float)h);
    float dec2 = log2f(rgeo);
    float rp1 = exp2f(dec2 * (float)(q + 1));
    float cs = (1.f - rp1) / (1.f - rgeo);
    float invs = rsqrtf(cs);
    float d = fmaxf(den * invs, 1.f);
    float scl = invs / d;
    float ss = 0.f;
    #pragma unroll
    for (int j = 0; j < 16; ++j) { float v = acc[j] * scl; acc[j] = v; ss += v * v; }
    ss += __shfl_xor(ss, 1); ss += __shfl_xor(ss, 2); ss += __shfl_xor(ss, 4);
    float rms = rsqrtf(ss * (1.f / DV) + 1e-6f);

    const u16* gbase = qkvg + ((size_t)(b * SEQ + q)) * QKVGN + 1024 + h * DV + c0;
    u16* obase = og + ((size_t)(b * SEQ + q)) * VDIM + h * DV + c0;
    #pragma unroll
    for (int j = 0; j < 16; ++j) {
        float gv = b2f(gbase[j]);
        float sig = 1.f / (1.f + __expf(-gv));
        obase[j] = f2b(gv * sig * acc[j] * rms);
    }
}

extern "C" void kernel_launch(void* const* d_in, const int* in_sizes, int n_in,
                              void* d_out, int out_size, void* d_ws, size_t ws_size,
                              hipStream_t stream)
{
    const float* x0    = (const float*)d_in[0];
    const float* Wq    = (const float*)d_in[1];
    const float* Wk    = (const float*)d_in[2];
    const float* Wv    = (const float*)d_in[3];
    const float* Wg    = (const float*)d_in[4];
    const float* Wo    = (const float*)d_in[5];
    const float* ln1w  = (const float*)d_in[6];
    const float* ln1b  = (const float*)d_in[7];
    const float* ln2w  = (const float*)d_in[8];
    const float* ln2b  = (const float*)d_in[9];
    const float* W1    = (const float*)d_in[10];
    const float* b1    = (const float*)d_in[11];
    const float* W2    = (const float*)d_in[12];
    const float* b2    = (const float*)d_in[13];

    char* ws = (char*)d_ws;
    size_t off = 0;
    auto alloc = [&](size_t bytes) { char* p = ws + off; off += (bytes + 255) & ~(size_t)255; return p; };

    float* sin_t = (float*)alloc(SEQ * DK * 4);
    float* cos_t = (float*)alloc(SEQ * DK * 4);
    u16* wqkvg_t = (u16*)alloc((size_t)3 * QKVGN * DMODEL * 2);
    u16* wo_t    = (u16*)alloc((size_t)3 * DMODEL * VDIM * 2);
    u16* w1_t    = (u16*)alloc((size_t)3 * FDIM * DMODEL * 2);
    u16* w2_t    = (u16*)alloc((size_t)3 * DMODEL * FDIM * 2);
    u16* qkvg    = (u16*)alloc((size_t)NROWS * QKVGN * 2);      // ff1 overlays (8MB<=12MB)
    u16* xln     = (u16*)alloc((size_t)NROWS * DMODEL * 2);     // also h2
    u16* vt      = (u16*)alloc((size_t)NB * NHEAD * DV * SEQ * 2);
    u16* ogb     = (u16*)alloc((size_t)NROWS * VDIM * 2);
    float* yb    = (float*)alloc((size_t)NROWS * DMODEL * 4);
    float* xbuf  = (float*)alloc((size_t)NROWS * DMODEL * 4);
    float* po    = (float*)alloc((size_t)8 * NSLOT * 32 * 128 * 4);  // 20MB; pW overlays (16MB)
    float* pden  = (float*)alloc((size_t)8 * NSLOT * 32 * 4);
    u16* ff1 = qkvg;
    u16* h2  = xln;
    float* pW = po;

    tables_kernel<<<(SEQ * DK + 255) / 256, 256, 0, stream>>>(sin_t, cos_t);
    dim3 tb(32, 8);
    const size_t WLQ = (size_t)QKVGN * DMODEL;
    wconv_kernel<<<dim3(8, 8, 3),  tb, 0, stream>>>(Wq, wqkvg_t,              DMODEL, DMODEL, (size_t)DMODEL*DMODEL, WLQ);
    wconv_kernel<<<dim3(8, 8, 3),  tb, 0, stream>>>(Wk, wqkvg_t + 256 * 256,  DMODEL, DMODEL, (size_t)DMODEL*DMODEL, WLQ);
    wconv_kernel<<<dim3(16, 8, 3), tb, 0, stream>>>(Wv, wqkvg_t + 512 * 256,  DMODEL, VDIM,   (size_t)DMODEL*VDIM,   WLQ);
    wconv_kernel<<<dim3(16, 8, 3), tb, 0, stream>>>(Wg, wqkvg_t + 1024 * 256, DMODEL, VDIM,   (size_t)DMODEL*VDIM,   WLQ);
    wconv_kernel<<<dim3(8, 16, 3), tb, 0, stream>>>(Wo, wo_t, VDIM,   DMODEL, (size_t)VDIM*DMODEL,   (size_t)VDIM*DMODEL);
    wconv_kernel<<<dim3(32, 8, 3), tb, 0, stream>>>(W1, w1_t, DMODEL, FDIM,   (size_t)DMODEL*FDIM,   (size_t)DMODEL*FDIM);
    wconv_kernel<<<dim3(8, 32, 3), tb, 0, stream>>>(W2, w2_t, FDIM,   DMODEL, (size_t)FDIM*DMODEL,   (size_t)FDIM*DMODEL);

    ln_kernel<<<NROWS, 256, 0, stream>>>(x0, ln1w, ln1b, xln);

    const float* xres = x0;   // residual input of current layer
    for (int i = 0; i < 3; ++i) {
        const u16* wqkvgi = wqkvg_t + (size_t)i * QKVGN * DMODEL;
        const u16* woi = wo_t + (size_t)i * DMODEL * VDIM;
        const u16* w1i = w1_t + (size_t)i * FDIM * DMODEL;
        const u16* w2i = w2_t + (size_t)i * DMODEL * FDIM;

        // fused Q|K|V|G projection with rotary epilogue on q,k
        gemm_bf16<0,0,1,1,0><<<dim3(QKVGN/64, NROWS/64), 256, 0, stream>>>(
            xln, wqkvgi, qkvg, nullptr, sin_t, cos_t, NROWS, QKVGN, DMODEL, 0);

        vtrans_kernel<<<dim3(SEQ/32, DV/32, NB*NHEAD), tb, 0, stream>>>(qkvg, vt);

        retention_p1<<<dim3(NSLOT, NB*NHEAD), 256, 0, stream>>>(qkvg, vt, po, pden);
        retention_p2<<<dim3(SEQ/32, NB*NHEAD), 256, 0, stream>>>(po, pden, qkvg, ogb);

        // y = og @ Wo + xres : split-K x2 into pW, combined in lncomb2
        gemm_bf16<0,0,0,0,1><<<dim3(DMODEL/64, NROWS/64, 2), 256, 0, stream>>>(
            ogb, woi, pW, nullptr, nullptr, nullptr, NROWS, DMODEL, VDIM, 256);
        lncomb2_kernel<<<NROWS, 256, 0, stream>>>(pW, xres,
            ln2w + i * DMODEL, ln2b + i * DMODEL, yb, h2);

        // ff1 = gelu(h2 @ W1 + b1)
        gemm_bf16<1,1,0,1,0><<<dim3(FDIM/64, NROWS/64), 256, 0, stream>>>(
            h2, w1i, ff1, b1 + (size_t)i * FDIM, nullptr, nullptr, NROWS, FDIM, DMODEL, 0);

        // x_next = ff1 @ W2 + b2 + yb : split-K x4 into pW
        gemm_bf16<0,0,0,0,1><<<dim3(DMODEL/64, NROWS/64, 4), 256, 0, stream>>>(
            ff1, w2i, pW, nullptr, nullptr, nullptr, NROWS, DMODEL, FDIM, 256);

        if (i < 2) {
            lncomb4_kernel<<<NROWS, 256, 0, stream>>>(pW, b2 + (size_t)i * DMODEL, yb,
                ln1w + (i + 1) * DMODEL, ln1b + (i + 1) * DMODEL, xbuf, xln);
            xres = xbuf;
        } else {
            comb4_kernel<<<NROWS, 256, 0, stream>>>(pW, b2 + (size_t)i * DMODEL, yb, (float*)d_out);
        }
    }
}